// Round 1
// baseline (1167.498 us; speedup 1.0000x reference)
//
#include <hip/hip_runtime.h>

#define D_FEAT 64
#define H_SIZE 32
#define N_CLASSES 10
#define NT 256

// ---------------- scatter-add kernels (edge-parallel, 1 lane per feature) ---

__global__ __launch_bounds__(NT) void scatter_add64(
    const float* __restrict__ feat, const int* __restrict__ src,
    const int* __restrict__ dst, float* __restrict__ agg, int n_edges) {
    int t = blockIdx.x * NT + threadIdx.x;
    int e = t >> 6, f = t & 63;
    if (e >= n_edges) return;
    int s = src[e], d = dst[e];               // same addr across 64 lanes -> broadcast
    atomicAdd(&agg[d * 64 + f], feat[s * 64 + f]);
}

__global__ __launch_bounds__(NT) void scatter_add32(
    const float* __restrict__ feat, const int* __restrict__ src,
    const int* __restrict__ dst, float* __restrict__ agg, int n_edges) {
    int t = blockIdx.x * NT + threadIdx.x;
    int e = t >> 5, f = t & 31;
    if (e >= n_edges) return;
    int s = src[e], d = dst[e];
    atomicAdd(&agg[d * 32 + f], feat[s * 32 + f]);
}

// ---------------- layer 1: h = relu(agg1 @ W1_rel^T + b1 + x @ W1_root^T) --

__global__ __launch_bounds__(NT) void node_layer1(
    const float* __restrict__ x, const float* __restrict__ agg,
    const float* __restrict__ W1_rel, const float* __restrict__ b1,
    const float* __restrict__ W1_root, float* __restrict__ h, int n_nodes) {
    __shared__ float sWrelT[D_FEAT * H_SIZE];   // [f][k] transposed: bank = k -> conflict-free
    __shared__ float sWrootT[D_FEAT * H_SIZE];
    __shared__ float sb[H_SIZE];
    for (int i = threadIdx.x; i < H_SIZE * D_FEAT; i += NT) {
        int k = i >> 6, f = i & 63;
        sWrelT[f * H_SIZE + k] = W1_rel[i];
        sWrootT[f * H_SIZE + k] = W1_root[i];
    }
    if (threadIdx.x < H_SIZE) sb[threadIdx.x] = b1[threadIdx.x];
    __syncthreads();

    int t = blockIdx.x * NT + threadIdx.x;
    int n = t >> 5, k = t & 31;
    if (n >= n_nodes) return;
    const float* ar = agg + n * D_FEAT;
    const float* xr = x + n * D_FEAT;
    float acc = sb[k];
#pragma unroll
    for (int f = 0; f < D_FEAT; ++f)
        acc += ar[f] * sWrelT[f * H_SIZE + k] + xr[f] * sWrootT[f * H_SIZE + k];
    h[n * H_SIZE + k] = fmaxf(acc, 0.f);
}

// ------- layer 2 + log-softmax + NLL loss (1 thread per node) --------------

__global__ __launch_bounds__(NT) void node_layer2_loss(
    const float* __restrict__ h, const float* __restrict__ agg2,
    const float* __restrict__ W2_rel, const float* __restrict__ b2,
    const float* __restrict__ W2_root, const int* __restrict__ y,
    float* __restrict__ loss, int n_nodes) {
    __shared__ float sWrel[N_CLASSES * H_SIZE];
    __shared__ float sWroot[N_CLASSES * H_SIZE];
    __shared__ float sb[N_CLASSES];
    for (int i = threadIdx.x; i < N_CLASSES * H_SIZE; i += NT) {
        sWrel[i] = W2_rel[i];
        sWroot[i] = W2_root[i];
    }
    if (threadIdx.x < N_CLASSES) sb[threadIdx.x] = b2[threadIdx.x];
    __syncthreads();

    int n = blockIdx.x * NT + threadIdx.x;
    float contrib = 0.f;
    if (n < n_nodes) {
        const float* ar = agg2 + n * H_SIZE;
        const float* hr = h + n * H_SIZE;
        float av[H_SIZE], hv[H_SIZE];
#pragma unroll
        for (int f = 0; f < H_SIZE; ++f) { av[f] = ar[f]; hv[f] = hr[f]; }
        float l[N_CLASSES];
#pragma unroll
        for (int c = 0; c < N_CLASSES; ++c) {
            float acc = sb[c];
#pragma unroll
            for (int f = 0; f < H_SIZE; ++f)   // LDS reads uniform across lanes -> broadcast
                acc += av[f] * sWrel[c * H_SIZE + f] + hv[f] * sWroot[c * H_SIZE + f];
            l[c] = acc;
        }
        float m = l[0];
#pragma unroll
        for (int c = 1; c < N_CLASSES; ++c) m = fmaxf(m, l[c]);
        float s = 0.f;
#pragma unroll
        for (int c = 0; c < N_CLASSES; ++c) s += expf(l[c] - m);
        float lse = m + logf(s);
        contrib = (lse - l[y[n]]) * (1.f / (float)n_nodes);
    }
    // block reduction: wave shuffle then cross-wave via LDS
    for (int o = 32; o > 0; o >>= 1) contrib += __shfl_down(contrib, o, 64);
    __shared__ float part[NT / 64];
    if ((threadIdx.x & 63) == 0) part[threadIdx.x >> 6] = contrib;
    __syncthreads();
    if (threadIdx.x == 0) {
        float v = 0.f;
#pragma unroll
        for (int w = 0; w < NT / 64; ++w) v += part[w];
        atomicAdd(loss, v);
    }
}

extern "C" void kernel_launch(void* const* d_in, const int* in_sizes, int n_in,
                              void* d_out, int out_size, void* d_ws, size_t ws_size,
                              hipStream_t stream) {
    const float* x       = (const float*)d_in[0];
    const int*   ei      = (const int*)d_in[1];
    const int*   y       = (const int*)d_in[2];
    const float* W1_rel  = (const float*)d_in[3];
    const float* b1_rel  = (const float*)d_in[4];
    const float* W1_root = (const float*)d_in[5];
    const float* W2_rel  = (const float*)d_in[6];
    const float* b2_rel  = (const float*)d_in[7];
    const float* W2_root = (const float*)d_in[8];
    float* loss = (float*)d_out;

    const int n_nodes = in_sizes[0] / D_FEAT;
    const int n_edges = in_sizes[1] / 2;
    const int* src = ei;
    const int* dst = ei + n_edges;

    // workspace layout: [agg: n_nodes*64 f32][h: n_nodes*32 f32]
    float* agg = (float*)d_ws;                       // reused for agg1 (64) and agg2 (32)
    float* h   = agg + (size_t)n_nodes * D_FEAT;

    // ---- layer 1 ----
    hipMemsetAsync(agg, 0, (size_t)n_nodes * D_FEAT * sizeof(float), stream);
    {
        long long tot = (long long)n_edges * 64;
        int blocks = (int)((tot + NT - 1) / NT);
        scatter_add64<<<blocks, NT, 0, stream>>>(x, src, dst, agg, n_edges);
    }
    {
        int blocks = (n_nodes * H_SIZE + NT - 1) / NT;
        node_layer1<<<blocks, NT, 0, stream>>>(x, agg, W1_rel, b1_rel, W1_root, h, n_nodes);
    }

    // ---- layer 2 ----
    hipMemsetAsync(agg, 0, (size_t)n_nodes * H_SIZE * sizeof(float), stream);
    {
        long long tot = (long long)n_edges * 32;
        int blocks = (int)((tot + NT - 1) / NT);
        scatter_add32<<<blocks, NT, 0, stream>>>(h, src, dst, agg, n_edges);
    }
    hipMemsetAsync(loss, 0, sizeof(float), stream);
    {
        int blocks = (n_nodes + NT - 1) / NT;
        node_layer2_loss<<<blocks, NT, 0, stream>>>(h, agg, W2_rel, b2_rel, W2_root, y,
                                                    loss, n_nodes);
    }
}

// Round 2
// 891.759 us; speedup vs baseline: 1.3092x; 1.3092x over previous
//
#include <hip/hip_runtime.h>

#define D_FEAT 64
#define H_SIZE 32
#define N_CLASSES 10
#define NT 256
#define SCAN_T 1024

// ---------------- CSR build ------------------------------------------------

__global__ __launch_bounds__(NT) void hist_kernel(
    const int* __restrict__ dst, int* __restrict__ rowptr, int n_edges) {
    int t = blockIdx.x * NT + threadIdx.x;
    if (t < n_edges) atomicAdd(&rowptr[dst[t] + 1], 1);
}

// single-block inclusive scan (a[0]=0, a[i+1]=counts -> rowptr)
__global__ __launch_bounds__(SCAN_T) void scan_kernel(int* __restrict__ a, int n) {
    __shared__ int lds[SCAN_T];
    int tid = threadIdx.x;
    int R = (n + SCAN_T - 1) / SCAN_T;
    int beg = tid * R, end = min(beg + R, n);
    int s = 0;
    for (int i = beg; i < end; ++i) s += a[i];
    lds[tid] = s;
    __syncthreads();
    for (int off = 1; off < SCAN_T; off <<= 1) {
        int v = (tid >= off) ? lds[tid - off] : 0;
        __syncthreads();
        lds[tid] += v;
        __syncthreads();
    }
    int run = lds[tid] - s;  // exclusive prefix of this segment
    for (int i = beg; i < end; ++i) {
        run += a[i];
        a[i] = run;
    }
}

__global__ __launch_bounds__(NT) void fill_kernel(
    const int* __restrict__ src, const int* __restrict__ dst,
    int* __restrict__ cursor, int* __restrict__ csr, int n_edges) {
    int t = blockIdx.x * NT + threadIdx.x;
    if (t >= n_edges) return;
    int p = atomicAdd(&cursor[dst[t]], 1);
    csr[p] = src[t];
}

// ---------------- dense pre-transforms -------------------------------------

// xr = x @ W1_rel^T ; xroot = x @ W1_root^T + b1   (thread = (node, k<32))
__global__ __launch_bounds__(NT) void dense1_kernel(
    const float* __restrict__ x, const float* __restrict__ W1_rel,
    const float* __restrict__ b1, const float* __restrict__ W1_root,
    float* __restrict__ xr, float* __restrict__ xroot, int n_nodes) {
    __shared__ float sWrelT[D_FEAT * H_SIZE];   // [f][k]
    __shared__ float sWrootT[D_FEAT * H_SIZE];
    __shared__ float sb[H_SIZE];
    for (int i = threadIdx.x; i < H_SIZE * D_FEAT; i += NT) {
        int k = i >> 6, f = i & 63;
        sWrelT[f * H_SIZE + k] = W1_rel[i];
        sWrootT[f * H_SIZE + k] = W1_root[i];
    }
    if (threadIdx.x < H_SIZE) sb[threadIdx.x] = b1[threadIdx.x];
    __syncthreads();

    int t = blockIdx.x * NT + threadIdx.x;
    int n = t >> 5, k = t & 31;
    if (n >= n_nodes) return;
    const float* xrow = x + (size_t)n * D_FEAT;
    float ar = 0.f, ao = 0.f;
#pragma unroll
    for (int f = 0; f < D_FEAT; ++f) {
        float xv = xrow[f];
        ar += xv * sWrelT[f * H_SIZE + k];
        ao += xv * sWrootT[f * H_SIZE + k];
    }
    xr[n * H_SIZE + k] = ar;
    xroot[n * H_SIZE + k] = ao + sb[k];
}

// h2 = h @ W2_rel^T ; hroot = h @ W2_root^T + b2  (stride-16 padded, c>=10 -> 0)
__global__ __launch_bounds__(NT) void dense2_kernel(
    const float* __restrict__ h, const float* __restrict__ W2_rel,
    const float* __restrict__ b2, const float* __restrict__ W2_root,
    float* __restrict__ h2, float* __restrict__ hroot, int n_nodes) {
    __shared__ float sWrelT[H_SIZE * 16];   // [j][c] stride 16
    __shared__ float sWrootT[H_SIZE * 16];
    __shared__ float sb[16];
    for (int i = threadIdx.x; i < H_SIZE * 16; i += NT) sWrelT[i] = sWrootT[i] = 0.f;
    __syncthreads();
    for (int i = threadIdx.x; i < N_CLASSES * H_SIZE; i += NT) {
        int c = i >> 5, j = i & 31;   // W2[c][j]
        sWrelT[j * 16 + c] = W2_rel[i];
        sWrootT[j * 16 + c] = W2_root[i];
    }
    if (threadIdx.x < 16) sb[threadIdx.x] = (threadIdx.x < N_CLASSES) ? b2[threadIdx.x] : 0.f;
    __syncthreads();

    int t = blockIdx.x * NT + threadIdx.x;
    int n = t >> 4, c = t & 15;
    if (n >= n_nodes) return;
    const float* hrow = h + (size_t)n * H_SIZE;
    float ar = 0.f, ao = 0.f;
#pragma unroll
    for (int j = 0; j < H_SIZE; ++j) {
        float hv = hrow[j];
        ar += hv * sWrelT[j * 16 + c];
        ao += hv * sWrootT[j * 16 + c];
    }
    bool valid = (c < N_CLASSES);
    h2[n * 16 + c] = valid ? ar : 0.f;
    hroot[n * 16 + c] = valid ? (ao + sb[c]) : 0.f;
}

// ---------------- gather aggregations --------------------------------------

// h = relu(gather_sum(xr) + xroot)   (32 lanes per node; h may alias xroot)
__global__ __launch_bounds__(NT) void gather1_kernel(
    const float* __restrict__ xr, const float* __restrict__ xroot,
    const int* __restrict__ rowptr, const int* __restrict__ csr,
    float* __restrict__ h, int n_nodes) {
    int t = blockIdx.x * NT + threadIdx.x;
    int n = t >> 5, f = t & 31;
    if (n >= n_nodes) return;
    int beg = rowptr[n], end = rowptr[n + 1];
    float acc = 0.f;
    int i = beg;
    for (; i + 1 < end; i += 2) {
        int s0 = csr[i], s1 = csr[i + 1];
        acc += xr[s0 * H_SIZE + f];
        acc += xr[s1 * H_SIZE + f];
    }
    if (i < end) acc += xr[csr[i] * H_SIZE + f];
    h[n * H_SIZE + f] = fmaxf(acc + xroot[n * H_SIZE + f], 0.f);
}

// logits = gather_sum(h2) + hroot; log-softmax + NLL, block-reduced into loss
__global__ __launch_bounds__(NT) void gather2_loss_kernel(
    const float* __restrict__ h2, const float* __restrict__ hroot,
    const int* __restrict__ rowptr, const int* __restrict__ csr,
    const int* __restrict__ y, float* __restrict__ loss,
    int n_nodes, float invN) {
    int t = blockIdx.x * NT + threadIdx.x;
    int n = t >> 4, c = t & 15;
    int lane = threadIdx.x & 63;
    bool active = (n < n_nodes);

    float logit = 0.f;
    int yv = 0;
    if (active) {
        int beg = rowptr[n], end = rowptr[n + 1];
        float acc = 0.f;
        int i = beg;
        for (; i + 1 < end; i += 2) {
            int s0 = csr[i], s1 = csr[i + 1];
            acc += h2[s0 * 16 + c];
            acc += h2[s1 * 16 + c];
        }
        if (i < end) acc += h2[csr[i] * 16 + c];
        logit = acc + hroot[n * 16 + c];
        yv = y[n];
    }
    // 16-lane-group softmax
    float lm = (active && c < N_CLASSES) ? logit : -INFINITY;
#pragma unroll
    for (int m = 1; m < 16; m <<= 1) lm = fmaxf(lm, __shfl_xor(lm, m, 64));
    float e = (active && c < N_CLASSES) ? expf(logit - lm) : 0.f;
#pragma unroll
    for (int m = 1; m < 16; m <<= 1) e += __shfl_xor(e, m, 64);
    float ly = __shfl(logit, (lane & ~15) + yv, 64);
    float contrib = (active && c == 0) ? (lm + logf(e) - ly) * invN : 0.f;

    // wave reduce then cross-wave
#pragma unroll
    for (int o = 32; o > 0; o >>= 1) contrib += __shfl_down(contrib, o, 64);
    __shared__ float part[NT / 64];
    if (lane == 0) part[threadIdx.x >> 6] = contrib;
    __syncthreads();
    if (threadIdx.x == 0) {
        float v = 0.f;
#pragma unroll
        for (int w = 0; w < NT / 64; ++w) v += part[w];
        atomicAdd(loss, v);
    }
}

// ---------------------------------------------------------------------------

extern "C" void kernel_launch(void* const* d_in, const int* in_sizes, int n_in,
                              void* d_out, int out_size, void* d_ws, size_t ws_size,
                              hipStream_t stream) {
    const float* x       = (const float*)d_in[0];
    const int*   ei      = (const int*)d_in[1];
    const int*   y       = (const int*)d_in[2];
    const float* W1_rel  = (const float*)d_in[3];
    const float* b1_rel  = (const float*)d_in[4];
    const float* W1_root = (const float*)d_in[5];
    const float* W2_rel  = (const float*)d_in[6];
    const float* b2_rel  = (const float*)d_in[7];
    const float* W2_root = (const float*)d_in[8];
    float* loss = (float*)d_out;

    const int n_nodes = in_sizes[0] / D_FEAT;
    const int n_edges = in_sizes[1] / 2;
    const int* src = ei;
    const int* dst = ei + n_edges;

    // workspace layout
    size_t off = 0;
    auto alloc = [&](size_t bytes) {
        void* p = (char*)d_ws + off;
        off = (off + bytes + 255) & ~(size_t)255;
        return p;
    };
    int*   rowptr = (int*)alloc((size_t)(n_nodes + 1) * 4);
    int*   cursor = (int*)alloc((size_t)n_nodes * 4);
    int*   csr    = (int*)alloc((size_t)n_edges * 4);
    float* xr     = (float*)alloc((size_t)n_nodes * H_SIZE * 4);
    float* xroot  = (float*)alloc((size_t)n_nodes * H_SIZE * 4);  // h aliases this
    float* h2     = (float*)alloc((size_t)n_nodes * 16 * 4);
    float* hroot  = (float*)alloc((size_t)n_nodes * 16 * 4);
    float* h = xroot;

    int eb = (n_edges + NT - 1) / NT;

    // ---- CSR build (shared by both layers) ----
    hipMemsetAsync(rowptr, 0, (size_t)(n_nodes + 1) * 4, stream);
    hist_kernel<<<eb, NT, 0, stream>>>(dst, rowptr, n_edges);
    scan_kernel<<<1, SCAN_T, 0, stream>>>(rowptr, n_nodes + 1);
    hipMemcpyAsync(cursor, rowptr, (size_t)n_nodes * 4, hipMemcpyDeviceToDevice, stream);
    fill_kernel<<<eb, NT, 0, stream>>>(src, dst, cursor, csr, n_edges);

    // ---- layer 1 ----
    {
        int blocks = (n_nodes * H_SIZE + NT - 1) / NT;
        dense1_kernel<<<blocks, NT, 0, stream>>>(x, W1_rel, b1_rel, W1_root, xr, xroot, n_nodes);
        gather1_kernel<<<blocks, NT, 0, stream>>>(xr, xroot, rowptr, csr, h, n_nodes);
    }

    // ---- layer 2 + loss ----
    hipMemsetAsync(loss, 0, sizeof(float), stream);
    {
        int blocks = (n_nodes * 16 + NT - 1) / NT;
        dense2_kernel<<<blocks, NT, 0, stream>>>(h, W2_rel, b2_rel, W2_root, h2, hroot, n_nodes);
        gather2_loss_kernel<<<blocks, NT, 0, stream>>>(h2, hroot, rowptr, csr, y, loss,
                                                       n_nodes, 1.f / (float)n_nodes);
    }
}